// Round 3
// baseline (4280.753 us; speedup 1.0000x reference)
//
#include <hip/hip_runtime.h>

#define T_STEPS 1024
#define BATCH   128
#define IDIM    256
#define HDIM    512
#define BH      (BATCH * HDIM)      // 65536
#define TBH     (T_STEPS * BH)      // 67108864

using short8  = __attribute__((ext_vector_type(8))) short;
using floatx4 = __attribute__((ext_vector_type(4))) float;

// ---------- bf16 helpers (RNE, finite inputs only) ----------
__device__ __forceinline__ unsigned short f2bf(float f) {
  unsigned u = __builtin_bit_cast(unsigned, f);
  u += 0x7FFFu + ((u >> 16) & 1u);
  return (unsigned short)(u >> 16);
}
__device__ __forceinline__ float bf2f(unsigned short h) {
  unsigned u = ((unsigned)h) << 16;
  return __builtin_bit_cast(float, u);
}
__device__ __forceinline__ float fast_tanh(float x) {
  // tanh(x) = 1 - 2/(e^{2x}+1); exp->inf / ->0 limits give +/-1 correctly
  float e = __expf(2.0f * x);
  return 1.0f - 2.0f * __builtin_amdgcn_rcpf(e + 1.0f);
}

// Convert 16 consecutive fp32 -> bf16 hi/lo planes, vector-store to LDS.
__device__ __forceinline__ void stage16(const float4* __restrict__ p,
                                        unsigned short* dhi, unsigned short* dlo) {
  short8 h0{}, h1{}, l0{}, l1{};
#pragma unroll
  for (int v = 0; v < 4; v++) {
    float4 fv = p[v];
    float fs[4] = {fv.x, fv.y, fv.z, fv.w};
#pragma unroll
    for (int e = 0; e < 4; e++) {
      int idx = v * 4 + e;
      unsigned short hh = f2bf(fs[e]);
      unsigned short ll = f2bf(fs[e] - bf2f(hh));
      if (idx < 8) { h0[idx] = (short)hh; l0[idx] = (short)ll; }
      else         { h1[idx - 8] = (short)hh; l1[idx - 8] = (short)ll; }
    }
  }
  *(short8*)(dhi)     = h0;
  *(short8*)(dhi + 8) = h1;
  *(short8*)(dlo)     = l0;
  *(short8*)(dlo + 8) = l1;
}

// ================= Kernel A: xw = x @ Wi^T  (written into d_out[0..TBH)) ==========
// (unchanged; ~430 us, secondary to the scan)
__global__ __launch_bounds__(256, 2) void xw_gemm(const float* __restrict__ x,
                                                  const float* __restrict__ Wi,
                                                  float* __restrict__ out) {
  __shared__ unsigned short Ahi[128 * 40], Alo[128 * 40];
  __shared__ unsigned short Bhi[128 * 40], Blo[128 * 40];
  const int bx   = blockIdx.x;
  const int m0   = (bx >> 2) * 128;
  const int n0   = (bx & 3) * 128;
  const int tid  = threadIdx.x;
  const int lane = tid & 63;
  const int wave = tid >> 6;
  const int q    = lane >> 4;
  const int ml   = lane & 15;
  const int wm   = (wave >> 1) * 64;
  const int wn   = (wave & 1) * 64;
  const int srow = tid & 127;   // staging row (both tiles are 128 x 32)
  const int skh  = tid >> 7;    // staging k-half (0/1), 16 floats each

  floatx4 acc[4][4];
#pragma unroll
  for (int i = 0; i < 4; i++)
#pragma unroll
    for (int j = 0; j < 4; j++)
      acc[i][j] = floatx4{0.f, 0.f, 0.f, 0.f};

  for (int kb = 0; kb < 8; kb++) {
    stage16((const float4*)(x  + (size_t)(m0 + srow) * IDIM + kb * 32 + skh * 16),
            &Ahi[srow * 40 + skh * 16], &Alo[srow * 40 + skh * 16]);
    stage16((const float4*)(Wi + (size_t)(n0 + srow) * IDIM + kb * 32 + skh * 16),
            &Bhi[srow * 40 + skh * 16], &Blo[srow * 40 + skh * 16]);
    __syncthreads();

    short8 ah[4], al[4], bh[4], bl[4];
#pragma unroll
    for (int f = 0; f < 4; f++) {
      ah[f] = *(const short8*)&Ahi[(wm + f * 16 + ml) * 40 + q * 8];
      al[f] = *(const short8*)&Alo[(wm + f * 16 + ml) * 40 + q * 8];
      bh[f] = *(const short8*)&Bhi[(wn + f * 16 + ml) * 40 + q * 8];
      bl[f] = *(const short8*)&Blo[(wn + f * 16 + ml) * 40 + q * 8];
    }
#pragma unroll
    for (int mf = 0; mf < 4; mf++)
#pragma unroll
      for (int nf = 0; nf < 4; nf++) {
        acc[mf][nf] = __builtin_amdgcn_mfma_f32_16x16x32_bf16(ah[mf], bh[nf], acc[mf][nf], 0, 0, 0);
        acc[mf][nf] = __builtin_amdgcn_mfma_f32_16x16x32_bf16(ah[mf], bl[nf], acc[mf][nf], 0, 0, 0);
        acc[mf][nf] = __builtin_amdgcn_mfma_f32_16x16x32_bf16(al[mf], bh[nf], acc[mf][nf], 0, 0, 0);
      }
    __syncthreads();
  }

#pragma unroll
  for (int mf = 0; mf < 4; mf++)
#pragma unroll
    for (int nf = 0; nf < 4; nf++)
#pragma unroll
      for (int r = 0; r < 4; r++)
        out[(size_t)(m0 + wm + mf * 16 + q * 4 + r) * HDIM + (n0 + wn + nf * 16 + ml)] =
            acc[mf][nf][r];
}

// ================= Kernel B: recurrence h_t = tanh(xw_t + h_{t-1} Wh^T) ==========
// 32 blocks = 8 batch-groups (16 rows) x 4 j-groups (128 cols). Wh slice in VGPRs.
//
// V5 changes (vs V4, protocol semantics preserved):
//  - Spin: SYSTEM-scope relaxed polls (global_load sc0 sc1 -> read-through to the
//    LLC where agent atomics execute). Every poll is fresh; no buffer_inv storm,
//    no stale-L2 staleness window (V4's relaxed polls could not see the flag and
//    only the every-4th acquire poll detected it). One agent acquire fence after
//    exit invalidates stale h lines. Safety net: acquire poll every 256 iters.
//  - Own-quarter MFMA hoisted BEFORE the spin: the block's own 128-col slice of
//    h_{t-1} is already in LDS (register-forwarded at end of step t-1), so 12 of
//    48 MFMAs run in the spin-wait shadow. Wh fragments stored ROTATED
//    (slot s holds chunk (jg*4 + s) & 15) so all register-array indices stay
//    compile-time (no scratch spill).
//  - xw prefetch for step t+1 issued before barrier #3 (which drains vmcnt
//    anyway) -> acc-init never stalls on a cold LLC read.
// Numerics: chunk accumulation order rotated per-jg (own-first). Perturbation
// ~2^-20 per step, far below the bf16 representation noise that sets the
// absmax (2^-8). Alarm threshold: absmax > ~0.01 -> revert rotation.
__global__ __launch_bounds__(512, 2) void rnn_scan(const float* __restrict__ Wh,
                                                   float* out,
                                                   unsigned* __restrict__ flags) {
  __shared__ unsigned short Hhi[16 * 520], Hlo[16 * 520];
  const int bg     = blockIdx.x & 7;
  const int jg     = blockIdx.x >> 3;
  const int b_base = bg * 16;
  const int j_base = jg * 128;
  const int tid    = threadIdx.x;
  const int lane   = tid & 63;
  const int wave   = tid >> 6;
  const int q      = lane >> 4;
  const int ml     = lane & 15;
  const int col    = j_base + wave * 16 + ml;  // this lane's output column
  const int rowq   = b_base + q * 4;           // first of this lane's 4 D-rows
  const int lrow   = q * 4;                    // LDS-local row base
  const int cown   = jg * 4;                   // own k-chunk base (own cols)

  // ---- Load Wh fragments into registers (hi/lo), ROTATED: slot s <-> chunk
  // (cown+s)&15. Slots 0..3 = own k-range (j_base..j_base+128). ----
  short8 bfh[16], bfl[16];
#pragma unroll
  for (int s = 0; s < 16; s++) {
    const int c = (cown + s) & 15;
    const float4* p = (const float4*)(Wh + (size_t)col * HDIM + c * 32 + q * 8);
    float4 u = p[0], v = p[1];
    float fs[8] = {u.x, u.y, u.z, u.w, v.x, v.y, v.z, v.w};
    short8 h{}, l{};
#pragma unroll
    for (int e = 0; e < 8; e++) {
      unsigned short hh = f2bf(fs[e]);
      h[e] = (short)hh;
      l[e] = (short)f2bf(fs[e] - bf2f(hh));
    }
    bfh[s] = h;
    bfl[s] = l;
  }

  unsigned* const myflags = flags + bg * T_STEPS;
  float xwv[4];  // xw slice for the NEXT step, prefetched one iteration early

  // ---- t = 0: h_0 = tanh(xw_0) ----
  {
    float hv[4];
#pragma unroll
    for (int r = 0; r < 4; r++) {
      size_t idx = (size_t)(rowq + r) * HDIM + col;
      hv[r] = fast_tanh(out[idx]);
      __hip_atomic_store(&out[idx], hv[r], __ATOMIC_RELAXED, __HIP_MEMORY_SCOPE_AGENT);
    }
    // own-slice h_0 -> LDS from registers (for step 1's own-quarter MFMA)
#pragma unroll
    for (int r = 0; r < 4; r++) {
      unsigned short hh = f2bf(hv[r]);
      Hhi[(lrow + r) * 520 + col] = hh;
      Hlo[(lrow + r) * 520 + col] = f2bf(hv[r] - bf2f(hh));
    }
    // prefetch xw for t=1 (out[BH..) was written by xw_gemm; untouched by scan)
#pragma unroll
    for (int r = 0; r < 4; r++) xwv[r] = out[(size_t)BH + (size_t)(rowq + r) * HDIM + col];
    __syncthreads();  // stores drained; LDS own-slice visible to all waves
    if (tid == 0)
      __hip_atomic_fetch_add(&myflags[0], 1u,
                             __ATOMIC_RELEASE, __HIP_MEMORY_SCOPE_AGENT);
  }

  for (int t = 1; t < T_STEPS; t++) {
    float* ot = out + (size_t)t * BH;
    const float* otm1 = out + (size_t)(t - 1) * BH;

    // ---- own-quarter MFMA (slots 0..3) — runs in the spin-wait shadow ----
    floatx4 acc = {xwv[0], xwv[1], xwv[2], xwv[3]};
#pragma unroll
    for (int s = 0; s < 4; s++) {
      const int c = (cown + s) & 15;
      short8 ahi = *(const short8*)&Hhi[ml * 520 + c * 32 + q * 8];
      short8 alo = *(const short8*)&Hlo[ml * 520 + c * 32 + q * 8];
      acc = __builtin_amdgcn_mfma_f32_16x16x32_bf16(ahi, bfh[s], acc, 0, 0, 0);
      acc = __builtin_amdgcn_mfma_f32_16x16x32_bf16(ahi, bfl[s], acc, 0, 0, 0);
      acc = __builtin_amdgcn_mfma_f32_16x16x32_bf16(alo, bfh[s], acc, 0, 0, 0);
    }

    // ---- wait for all 4 j-blocks of this batch group to finish step t-1 ----
    if (tid == 0) {
      int k = 0;
      for (;;) {
        // SYSTEM-scope relaxed: sc0|sc1 read-through to LLC (where the agent
        // atomics land) -> fresh every poll, no cache invalidate.
        unsigned v = __hip_atomic_load(&myflags[t - 1],
                                       __ATOMIC_RELAXED, __HIP_MEMORY_SCOPE_SYSTEM);
        if (v >= 4u) break;
        if ((++k & 255) == 0) {
          // safety net: guaranteed-progress acquire poll (buffer_inv)
          v = __hip_atomic_load(&myflags[t - 1],
                                __ATOMIC_ACQUIRE, __HIP_MEMORY_SCOPE_AGENT);
          if (v >= 4u) break;
        }
        __builtin_amdgcn_s_sleep(1);
      }
      __builtin_amdgcn_fence(__ATOMIC_ACQUIRE, "agent");
    }
    __syncthreads();  // #1: block observes tid0's acquire

    // ---- stage the 3 PARTNER slices of h_{t-1} into LDS as bf16 hi/lo ----
    if (tid < 384) {
      const int s   = tid >> 7;                   // partner index 0..2
      const int pc  = ((jg + 1 + s) & 3) * 128;   // partner col base
      const int row = (tid >> 3) & 15;            // 0..15
      const int k0  = (tid & 7) * 16;             // 0..112, 16 floats
      stage16((const float4*)(otm1 + (size_t)(b_base + row) * HDIM + pc + k0),
              &Hhi[row * 520 + pc + k0], &Hlo[row * 520 + pc + k0]);
    }
    __syncthreads();  // #2: LDS A-tile complete

    // ---- remaining 12 chunks (slots 4..15) ----
#pragma unroll
    for (int s = 4; s < 16; s++) {
      const int c = (cown + s) & 15;
      short8 ahi = *(const short8*)&Hhi[ml * 520 + c * 32 + q * 8];
      short8 alo = *(const short8*)&Hlo[ml * 520 + c * 32 + q * 8];
      acc = __builtin_amdgcn_mfma_f32_16x16x32_bf16(ahi, bfh[s], acc, 0, 0, 0);
      acc = __builtin_amdgcn_mfma_f32_16x16x32_bf16(ahi, bfl[s], acc, 0, 0, 0);
      acc = __builtin_amdgcn_mfma_f32_16x16x32_bf16(alo, bfh[s], acc, 0, 0, 0);
    }

    float hv[4];
#pragma unroll
    for (int r = 0; r < 4; r++) {
      hv[r] = fast_tanh(acc[r]);
      __hip_atomic_store(&ot[(size_t)(rowq + r) * HDIM + col], hv[r],
                         __ATOMIC_RELAXED, __HIP_MEMORY_SCOPE_AGENT);
      if (t == T_STEPS - 1)
        out[(size_t)TBH + (size_t)(rowq + r) * HDIM + col] = hv[r];  // h_final tail
    }

    // prefetch xw for step t+1 (rides the vmcnt(0) drain at barrier #3)
    if (t + 1 < T_STEPS) {
#pragma unroll
      for (int r = 0; r < 4; r++)
        xwv[r] = out[(size_t)(t + 1) * BH + (size_t)(rowq + r) * HDIM + col];
    }

    __syncthreads();  // #3: all waves' stores (and prefetch) drained
    if (tid == 0)
      __hip_atomic_fetch_add(&myflags[t], 1u,
                             __ATOMIC_RELEASE, __HIP_MEMORY_SCOPE_AGENT);

    // own-slice h_t -> LDS from registers for step t+1's own-quarter MFMA
#pragma unroll
    for (int r = 0; r < 4; r++) {
      unsigned short hh = f2bf(hv[r]);
      Hhi[(lrow + r) * 520 + col] = hh;
      Hlo[(lrow + r) * 520 + col] = f2bf(hv[r] - bf2f(hh));
    }
    __syncthreads();  // #0: own-slice visible to all waves before next iter's MFMA
  }
}

extern "C" void kernel_launch(void* const* d_in, const int* in_sizes, int n_in,
                              void* d_out, int out_size, void* d_ws, size_t ws_size,
                              hipStream_t stream) {
  const float* x  = (const float*)d_in[0];   // [T,B,I]
  const float* Wi = (const float*)d_in[1];   // [H,I]
  const float* Wh = (const float*)d_in[2];   // [H,H]
  float* out      = (float*)d_out;           // [T,B,H] ++ [B,H]
  unsigned* flags = (unsigned*)d_ws;         // 8 groups x 1024 steps

  hipMemsetAsync(d_ws, 0, 8 * T_STEPS * sizeof(unsigned), stream);

  // xw -> d_out[0..TBH)
  xw_gemm<<<dim3((131072 / 128) * (HDIM / 128)), dim3(256), 0, stream>>>(x, Wi, out);

  // sequential scan, in-place over d_out
  rnn_scan<<<dim3(32), dim3(512), 0, stream>>>(Wh, out, flags);
}

// Round 4
// 3654.305 us; speedup vs baseline: 1.1714x; 1.1714x over previous
//
#include <hip/hip_runtime.h>

#define T_STEPS 1024
#define BATCH   128
#define IDIM    256
#define HDIM    512
#define BH      (BATCH * HDIM)      // 65536
#define TBH     (T_STEPS * BH)      // 67108864

using short8  = __attribute__((ext_vector_type(8))) short;
using floatx4 = __attribute__((ext_vector_type(4))) float;

// ---------- bf16 helpers (RNE, finite inputs only) ----------
__device__ __forceinline__ unsigned short f2bf(float f) {
  unsigned u = __builtin_bit_cast(unsigned, f);
  u += 0x7FFFu + ((u >> 16) & 1u);
  return (unsigned short)(u >> 16);
}
__device__ __forceinline__ float bf2f(unsigned short h) {
  unsigned u = ((unsigned)h) << 16;
  return __builtin_bit_cast(float, u);
}
__device__ __forceinline__ float fast_tanh(float x) {
  // tanh(x) = 1 - 2/(e^{2x}+1); exp->inf / ->0 limits give +/-1 correctly
  float e = __expf(2.0f * x);
  return 1.0f - 2.0f * __builtin_amdgcn_rcpf(e + 1.0f);
}

// Convert 16 consecutive fp32 -> bf16 hi/lo planes, vector-store to LDS.
__device__ __forceinline__ void stage16(const float4* __restrict__ p,
                                        unsigned short* dhi, unsigned short* dlo) {
  short8 h0{}, h1{}, l0{}, l1{};
#pragma unroll
  for (int v = 0; v < 4; v++) {
    float4 fv = p[v];
    float fs[4] = {fv.x, fv.y, fv.z, fv.w};
#pragma unroll
    for (int e = 0; e < 4; e++) {
      int idx = v * 4 + e;
      unsigned short hh = f2bf(fs[e]);
      unsigned short ll = f2bf(fs[e] - bf2f(hh));
      if (idx < 8) { h0[idx] = (short)hh; l0[idx] = (short)ll; }
      else         { h1[idx - 8] = (short)hh; l1[idx - 8] = (short)ll; }
    }
  }
  *(short8*)(dhi)     = h0;
  *(short8*)(dhi + 8) = h1;
  *(short8*)(dlo)     = l0;
  *(short8*)(dlo + 8) = l1;
}

// ================= Kernel A: xw = x @ Wi^T  (written into d_out[0..TBH)) ==========
// (unchanged; ~430 us, secondary to the scan)
__global__ __launch_bounds__(256, 2) void xw_gemm(const float* __restrict__ x,
                                                  const float* __restrict__ Wi,
                                                  float* __restrict__ out) {
  __shared__ unsigned short Ahi[128 * 40], Alo[128 * 40];
  __shared__ unsigned short Bhi[128 * 40], Blo[128 * 40];
  const int bx   = blockIdx.x;
  const int m0   = (bx >> 2) * 128;
  const int n0   = (bx & 3) * 128;
  const int tid  = threadIdx.x;
  const int lane = tid & 63;
  const int wave = tid >> 6;
  const int q    = lane >> 4;
  const int ml   = lane & 15;
  const int wm   = (wave >> 1) * 64;
  const int wn   = (wave & 1) * 64;
  const int srow = tid & 127;   // staging row (both tiles are 128 x 32)
  const int skh  = tid >> 7;    // staging k-half (0/1), 16 floats each

  floatx4 acc[4][4];
#pragma unroll
  for (int i = 0; i < 4; i++)
#pragma unroll
    for (int j = 0; j < 4; j++)
      acc[i][j] = floatx4{0.f, 0.f, 0.f, 0.f};

  for (int kb = 0; kb < 8; kb++) {
    stage16((const float4*)(x  + (size_t)(m0 + srow) * IDIM + kb * 32 + skh * 16),
            &Ahi[srow * 40 + skh * 16], &Alo[srow * 40 + skh * 16]);
    stage16((const float4*)(Wi + (size_t)(n0 + srow) * IDIM + kb * 32 + skh * 16),
            &Bhi[srow * 40 + skh * 16], &Blo[srow * 40 + skh * 16]);
    __syncthreads();

    short8 ah[4], al[4], bh[4], bl[4];
#pragma unroll
    for (int f = 0; f < 4; f++) {
      ah[f] = *(const short8*)&Ahi[(wm + f * 16 + ml) * 40 + q * 8];
      al[f] = *(const short8*)&Alo[(wm + f * 16 + ml) * 40 + q * 8];
      bh[f] = *(const short8*)&Bhi[(wn + f * 16 + ml) * 40 + q * 8];
      bl[f] = *(const short8*)&Blo[(wn + f * 16 + ml) * 40 + q * 8];
    }
#pragma unroll
    for (int mf = 0; mf < 4; mf++)
#pragma unroll
      for (int nf = 0; nf < 4; nf++) {
        acc[mf][nf] = __builtin_amdgcn_mfma_f32_16x16x32_bf16(ah[mf], bh[nf], acc[mf][nf], 0, 0, 0);
        acc[mf][nf] = __builtin_amdgcn_mfma_f32_16x16x32_bf16(ah[mf], bl[nf], acc[mf][nf], 0, 0, 0);
        acc[mf][nf] = __builtin_amdgcn_mfma_f32_16x16x32_bf16(al[mf], bh[nf], acc[mf][nf], 0, 0, 0);
      }
    __syncthreads();
  }

#pragma unroll
  for (int mf = 0; mf < 4; mf++)
#pragma unroll
    for (int nf = 0; nf < 4; nf++)
#pragma unroll
      for (int r = 0; r < 4; r++)
        out[(size_t)(m0 + wm + mf * 16 + q * 4 + r) * HDIM + (n0 + wn + nf * 16 + ml)] =
            acc[mf][nf][r];
}

// ================= Kernel B: recurrence h_t = tanh(xw_t + h_{t-1} Wh^T) ==========
// 32 blocks = 8 batch-groups (16 rows) x 4 j-groups (128 cols). Wh slice in VGPRs.
//
// V6 = V4 (measured 3265 us) + own-quarter hoist ONLY, restructured:
//  - Spin: V4's measured-good hybrid (relaxed agent polls + acquire every 4th,
//    one agent acquire fence after exit). [V5's system-scope spin reverted:
//    unproven, confounded.]
//  - xw prefetch: V4's placement — issued at LOOP TOP, consumed after barrier
//    #2 (~2000 cyc later; fully hidden by spin+stage). [V5 issued it before the
//    vmcnt(0)-draining barrier #3, putting 4 cold LLC reads on the serial
//    release chain — the main round-3 regression.]
//  - Own-quarter hoist (kept from V5): the block's own 128-col slice of h_{t-1}
//    is register-forwarded into LDS at end of step t-1; its 12 MFMAs run into a
//    ZERO-initialized accumulator BEFORE the spin (overlapping flag
//    propagation); xwv is added after barrier #2. Wh fragments stored ROTATED
//    (slot s <-> chunk (jg*4+s)&15) so all reg indices are compile-time.
// Numerics: accumulation order = own-chunks + xw + remaining-chunks. Reorder
// perturbation ~2^-20/step << bf16 representation noise (absmax 2^-8).
// Alarm: absmax > 0.01 -> revert rotation/hoist.
__global__ __launch_bounds__(512, 2) void rnn_scan(const float* __restrict__ Wh,
                                                   float* out,
                                                   unsigned* __restrict__ flags) {
  __shared__ unsigned short Hhi[16 * 520], Hlo[16 * 520];
  const int bg     = blockIdx.x & 7;
  const int jg     = blockIdx.x >> 3;
  const int b_base = bg * 16;
  const int j_base = jg * 128;
  const int tid    = threadIdx.x;
  const int lane   = tid & 63;
  const int wave   = tid >> 6;
  const int q      = lane >> 4;
  const int ml     = lane & 15;
  const int col    = j_base + wave * 16 + ml;  // this lane's output column
  const int rowq   = b_base + q * 4;           // first of this lane's 4 D-rows
  const int lrow   = q * 4;                    // LDS-local row base
  const int cown   = jg * 4;                   // own k-chunk base (own cols)

  // ---- Load Wh fragments into registers (hi/lo), ROTATED: slot s <-> chunk
  // (cown+s)&15. Slots 0..3 = own k-range (j_base..j_base+128). ----
  short8 bfh[16], bfl[16];
#pragma unroll
  for (int s = 0; s < 16; s++) {
    const int c = (cown + s) & 15;
    const float4* p = (const float4*)(Wh + (size_t)col * HDIM + c * 32 + q * 8);
    float4 u = p[0], v = p[1];
    float fs[8] = {u.x, u.y, u.z, u.w, v.x, v.y, v.z, v.w};
    short8 h{}, l{};
#pragma unroll
    for (int e = 0; e < 8; e++) {
      unsigned short hh = f2bf(fs[e]);
      h[e] = (short)hh;
      l[e] = (short)f2bf(fs[e] - bf2f(hh));
    }
    bfh[s] = h;
    bfl[s] = l;
  }

  unsigned* const myflags = flags + bg * T_STEPS;

  // ---- t = 0: h_0 = tanh(xw_0) ----
  {
    float hv[4];
#pragma unroll
    for (int r = 0; r < 4; r++) {
      size_t idx = (size_t)(rowq + r) * HDIM + col;
      hv[r] = fast_tanh(out[idx]);
      __hip_atomic_store(&out[idx], hv[r], __ATOMIC_RELAXED, __HIP_MEMORY_SCOPE_AGENT);
    }
    // own-slice h_0 -> LDS from registers (for step 1's own-quarter MFMA)
#pragma unroll
    for (int r = 0; r < 4; r++) {
      unsigned short hh = f2bf(hv[r]);
      Hhi[(lrow + r) * 520 + col] = hh;
      Hlo[(lrow + r) * 520 + col] = f2bf(hv[r] - bf2f(hh));
    }
    __syncthreads();  // stores drained; LDS own-slice visible to all waves
    if (tid == 0)
      __hip_atomic_fetch_add(&myflags[0], 1u,
                             __ATOMIC_RELEASE, __HIP_MEMORY_SCOPE_AGENT);
  }

  for (int t = 1; t < T_STEPS; t++) {
    float* ot         = out + (size_t)t * BH;
    const float* otm1 = out + (size_t)(t - 1) * BH;

    // Prefetch own xw slice (out[t] is only ever written by THIS block) — the
    // loads overlap the own-quarter MFMA, spin, and staging below; consumed
    // after barrier #2.
    float xwv[4];
#pragma unroll
    for (int r = 0; r < 4; r++) xwv[r] = ot[(size_t)(rowq + r) * HDIM + col];

    // ---- own-quarter MFMA (slots 0..3), ZERO-init acc — own slice of h_{t-1}
    // is already in LDS (register-forwarded). Runs while partner flags are
    // still propagating through the LLC. ----
    floatx4 acc = {0.f, 0.f, 0.f, 0.f};
#pragma unroll
    for (int s = 0; s < 4; s++) {
      const int c = (cown + s) & 15;
      short8 ahi = *(const short8*)&Hhi[ml * 520 + c * 32 + q * 8];
      short8 alo = *(const short8*)&Hlo[ml * 520 + c * 32 + q * 8];
      acc = __builtin_amdgcn_mfma_f32_16x16x32_bf16(ahi, bfh[s], acc, 0, 0, 0);
      acc = __builtin_amdgcn_mfma_f32_16x16x32_bf16(ahi, bfl[s], acc, 0, 0, 0);
      acc = __builtin_amdgcn_mfma_f32_16x16x32_bf16(alo, bfh[s], acc, 0, 0, 0);
    }

    // ---- wait for all 4 j-blocks of this batch group to finish step t-1 ----
    // (V4 hybrid: relaxed agent polls, acquire every 4th -> bounded staleness)
    if (tid == 0) {
      int k = 0;
      for (;;) {
        unsigned v = __hip_atomic_load(&myflags[t - 1],
                                       __ATOMIC_RELAXED, __HIP_MEMORY_SCOPE_AGENT);
        if (v >= 4u) break;
        if ((k++ & 3) == 3) {
          v = __hip_atomic_load(&myflags[t - 1],
                                __ATOMIC_ACQUIRE, __HIP_MEMORY_SCOPE_AGENT);
          if (v >= 4u) break;
        }
        __builtin_amdgcn_s_sleep(1);
      }
      __builtin_amdgcn_fence(__ATOMIC_ACQUIRE, "agent");
    }
    __syncthreads();  // #1: block observes tid0's acquire

    // ---- stage the 3 PARTNER slices of h_{t-1} into LDS as bf16 hi/lo ----
    if (tid < 384) {
      const int s   = tid >> 7;                   // partner index 0..2
      const int pc  = ((jg + 1 + s) & 3) * 128;   // partner col base
      const int row = (tid >> 3) & 15;            // 0..15
      const int k0  = (tid & 7) * 16;             // 0..112, 16 floats
      stage16((const float4*)(otm1 + (size_t)(b_base + row) * HDIM + pc + k0),
              &Hhi[row * 520 + pc + k0], &Hlo[row * 520 + pc + k0]);
    }
    __syncthreads();  // #2: LDS A-tile complete

    // add xw (prefetched at loop top; vmcnt wait lands here, fully hidden)
#pragma unroll
    for (int r = 0; r < 4; r++) acc[r] += xwv[r];

    // ---- remaining 12 chunks (slots 4..15) ----
#pragma unroll
    for (int s = 4; s < 16; s++) {
      const int c = (cown + s) & 15;
      short8 ahi = *(const short8*)&Hhi[ml * 520 + c * 32 + q * 8];
      short8 alo = *(const short8*)&Hlo[ml * 520 + c * 32 + q * 8];
      acc = __builtin_amdgcn_mfma_f32_16x16x32_bf16(ahi, bfh[s], acc, 0, 0, 0);
      acc = __builtin_amdgcn_mfma_f32_16x16x32_bf16(ahi, bfl[s], acc, 0, 0, 0);
      acc = __builtin_amdgcn_mfma_f32_16x16x32_bf16(alo, bfh[s], acc, 0, 0, 0);
    }

    float hv[4];
#pragma unroll
    for (int r = 0; r < 4; r++) {
      hv[r] = fast_tanh(acc[r]);
      __hip_atomic_store(&ot[(size_t)(rowq + r) * HDIM + col], hv[r],
                         __ATOMIC_RELAXED, __HIP_MEMORY_SCOPE_AGENT);
      if (t == T_STEPS - 1)
        out[(size_t)TBH + (size_t)(rowq + r) * HDIM + col] = hv[r];  // h_final tail
    }
    __syncthreads();  // #3: all waves' stores drained (no loads pending here —
                      //     release is never delayed by a prefetch)
    if (tid == 0)
      __hip_atomic_fetch_add(&myflags[t], 1u,
                             __ATOMIC_RELEASE, __HIP_MEMORY_SCOPE_AGENT);

    // own-slice h_t -> LDS from registers for step t+1's own-quarter MFMA
#pragma unroll
    for (int r = 0; r < 4; r++) {
      unsigned short hh = f2bf(hv[r]);
      Hhi[(lrow + r) * 520 + col] = hh;
      Hlo[(lrow + r) * 520 + col] = f2bf(hv[r] - bf2f(hh));
    }
    __syncthreads();  // #0: own-slice visible to all waves before next iter's MFMA
  }
}

extern "C" void kernel_launch(void* const* d_in, const int* in_sizes, int n_in,
                              void* d_out, int out_size, void* d_ws, size_t ws_size,
                              hipStream_t stream) {
  const float* x  = (const float*)d_in[0];   // [T,B,I]
  const float* Wi = (const float*)d_in[1];   // [H,I]
  const float* Wh = (const float*)d_in[2];   // [H,H]
  float* out      = (float*)d_out;           // [T,B,H] ++ [B,H]
  unsigned* flags = (unsigned*)d_ws;         // 8 groups x 1024 steps

  hipMemsetAsync(d_ws, 0, 8 * T_STEPS * sizeof(unsigned), stream);

  // xw -> d_out[0..TBH)
  xw_gemm<<<dim3((131072 / 128) * (HDIM / 128)), dim3(256), 0, stream>>>(x, Wi, out);

  // sequential scan, in-place over d_out
  rnn_scan<<<dim3(32), dim3(512), 0, stream>>>(Wh, out, flags);
}